// Round 5
// baseline (225.831 us; speedup 1.0000x reference)
//
#include <hip/hip_runtime.h>

typedef __bf16 bf16;
typedef __bf16 bf16x8 __attribute__((ext_vector_type(8)));
typedef float f32x4 __attribute__((ext_vector_type(4)));

// B_Nq = B_Ns = 16, C = 512, P = 1024, TAU*C = 256. I/O fp32; GEMMs bf16 MFMA.

#define GLL16(g, l)                                                             \
    __builtin_amdgcn_global_load_lds((const __attribute__((address_space(1))) void*)(g), \
                                     (__attribute__((address_space(3))) void*)(l), 16, 0, 0)

__device__ inline float wave_reduce_sum(float v) {
#pragma unroll
    for (int m = 32; m >= 1; m >>= 1) v += __shfl_xor(v, m, 64);
    return v;
}
__device__ inline float wave_reduce_max(float v) {
#pragma unroll
    for (int m = 32; m >= 1; m >>= 1) v = fmaxf(v, __shfl_xor(v, m, 64));
    return v;
}

// K0: prep — fs_mean (fp32 + bf16 + transposed bf16). grid (32 p-tiles, 16 c-tiles).
__global__ void k_prep(const float* __restrict__ fs, float* __restrict__ fsm32,
                       bf16* __restrict__ fsm16, bf16* __restrict__ fsmT) {
    __shared__ bf16 tile[32][33];
    int p0 = blockIdx.x * 32, c0 = blockIdx.y * 32;
    int t = threadIdx.x, tx = t & 31, ty = t >> 5;
#pragma unroll
    for (int i = 0; i < 4; ++i) {
        size_t off = (size_t)(c0 + ty + 8 * i) * 1024 + p0 + tx;
        float s = 0.f;
#pragma unroll
        for (int b = 0; b < 16; ++b) s += fs[(size_t)b * 524288 + off];
        s *= (1.f / 16.f);
        fsm32[off] = s;
        bf16 h = (bf16)s;
        fsm16[off] = h;
        tile[ty + 8 * i][tx] = h;
    }
    __syncthreads();
#pragma unroll
    for (int i = 0; i < 4; ++i)
        fsmT[(size_t)(p0 + ty + 8 * i) * 512 + c0 + tx] = tile[tx][ty + 8 * i];
}

// K1: rm[c] = rowmean(fs_mean[c,:]); u[c] = wsq[c]*wsk[c]*rm[c]/256
__global__ void k_u(const float* __restrict__ fsm32, const float* __restrict__ wsq,
                    const float* __restrict__ wsk, float* __restrict__ u,
                    float* __restrict__ rm) {
    int c = blockIdx.x;
    int t = threadIdx.x;
    float s = 0.f;
#pragma unroll
    for (int j = 0; j < 4; ++j) s += fsm32[(size_t)c * 1024 + t + 256 * j];
    s = wave_reduce_sum(s);
    __shared__ float red[4];
    int w = t >> 6, lane = t & 63;
    if (lane == 0) red[w] = s;
    __syncthreads();
    if (t == 0) {
        float rmv = (red[0] + red[1] + red[2] + red[3]) * (1.f / 1024.f);
        rm[c] = rmv;
        u[c] = wsq[c] * wsk[c] * rmv * (1.f / 256.f);
    }
}

// K2: G[b,c,d] = sum_p f_q[b,c,p]*fsm16[d,p] — 64(c)x128(d) tile, K=1024.
// A is fp32 global: float4 loads + in-reg cvt + ds_write; B via global_load_lds.
__global__ void k_gemm1(const float* __restrict__ A, const bf16* __restrict__ B,
                        float* __restrict__ G) {
    __shared__ alignas(16) bf16 As[64 * 32];
    __shared__ alignas(16) bf16 Bs[128 * 32];
    const int dt = blockIdx.x, ct = blockIdx.y, b = blockIdx.z;
    const int t = threadIdx.x, w = t >> 6, lane = t & 63;
    const int quad = lane >> 4, r15 = lane & 15;
    const float* Abase = A + ((size_t)(b * 512 + ct * 64)) * 1024;
    const bf16* Bbase = B + ((size_t)(dt * 128)) * 1024;
    const int sr = t >> 2, sc = (t & 3) * 8;
    f32x4 acc[8] = {};
    for (int k0 = 0; k0 < 1024; k0 += 32) {
        float4 a0 = *(const float4*)(Abase + (size_t)sr * 1024 + k0 + sc);
        float4 a1 = *(const float4*)(Abase + (size_t)sr * 1024 + k0 + sc + 4);
        GLL16(Bbase + (size_t)sr * 1024 + k0 + sc, Bs + t * 8);
        GLL16(Bbase + (size_t)(sr + 64) * 1024 + k0 + sc, Bs + (t + 256) * 8);
        bf16x8 ah = {(bf16)a0.x, (bf16)a0.y, (bf16)a0.z, (bf16)a0.w,
                     (bf16)a1.x, (bf16)a1.y, (bf16)a1.z, (bf16)a1.w};
        *(bf16x8*)(As + sr * 32 + sc) = ah;
        __syncthreads();
        bf16x8 af = *(const bf16x8*)(As + (w * 16 + r15) * 32 + quad * 8);
#pragma unroll
        for (int j = 0; j < 8; ++j) {
            bf16x8 bfr = *(const bf16x8*)(Bs + (j * 16 + r15) * 32 + quad * 8);
            acc[j] = __builtin_amdgcn_mfma_f32_16x16x32_bf16(af, bfr, acc[j], 0, 0, 0);
        }
        __syncthreads();
    }
    float* g = G + ((size_t)(b * 512 + ct * 64 + w * 16 + quad * 4)) * 512 + dt * 128 + r15;
#pragma unroll
    for (int j = 0; j < 8; ++j)
#pragma unroll
        for (int ii = 0; ii < 4; ++ii)
            g[(size_t)ii * 512 + j * 16] = acc[j][ii];
}

// K3: row softmax of G*wq[c]*wk[d]/P -> Acw (folds wv); r[b,c] = sum_d Acw*rm[d]
__global__ void k_softmax_ac(const float* __restrict__ G, const float* __restrict__ wq,
                             const float* __restrict__ wk, const float* __restrict__ wv,
                             const float* __restrict__ rm, bf16* __restrict__ Acw,
                             float* __restrict__ r) {
    int row = blockIdx.x * 4 + (threadIdx.x >> 6);  // b*512 + c
    int lane = threadIdx.x & 63;
    int c = row & 511;
    const float* g = G + (size_t)row * 512;
    float sc = wq[c] * (1.f / 1024.f);
    float v[8];
    float mx = -3.4e38f;
#pragma unroll
    for (int j = 0; j < 8; ++j) {
        int d = lane + 64 * j;
        v[j] = g[d] * sc * wk[d];
        mx = fmaxf(mx, v[j]);
    }
    mx = wave_reduce_max(mx);
    float sum = 0.f;
#pragma unroll
    for (int j = 0; j < 8; ++j) {
        v[j] = __expf(v[j] - mx);
        sum += v[j];
    }
    sum = wave_reduce_sum(sum);
    float inv = 1.f / sum;
    bf16* o = Acw + (size_t)row * 512;
    float rsum = 0.f;
#pragma unroll
    for (int j = 0; j < 8; ++j) {
        int d = lane + 64 * j;
        float aw = v[j] * inv * wv[d];
        o[d] = (bf16)aw;
        rsum += aw * rm[d];
    }
    rsum = wave_reduce_sum(rsum);
    if (lane == 0) r[row] = rsum;
}

// K4: tbp[half,b,d] = sum_{c in half} u[c]*Acw[b,c,d]   (grid (2,16,2))
__global__ void k_t(const bf16* __restrict__ Acw, const float* __restrict__ u,
                    float* __restrict__ tbp) {
    int half = blockIdx.z, b = blockIdx.y;
    int d = blockIdx.x * 256 + threadIdx.x;
    const bf16* base = Acw + (size_t)b * 262144 + (size_t)half * 256 * 512 + d;
    const float* uu = u + half * 256;
    float s = 0.f;
#pragma unroll 16
    for (int c = 0; c < 256; ++c) s += uu[c] * (float)base[(size_t)c * 512];
    tbp[(half * 16 + b) * 512 + d] = s;
}

// K5: out[b,c,p] = fq + lam*sum_d Acw[b,c,d]*fsmT[p,d] — 64(c)x128(p) tile, K=512
__global__ void k_gemm2(const bf16* __restrict__ A, const bf16* __restrict__ B,
                        const float* __restrict__ fq, const float* __restrict__ lamp,
                        float* __restrict__ out) {
    __shared__ alignas(16) bf16 As[64 * 32];
    __shared__ alignas(16) bf16 Bs[128 * 32];
    const int pt = blockIdx.x, ct = blockIdx.y, b = blockIdx.z;
    const int t = threadIdx.x, w = t >> 6, lane = t & 63;
    const int quad = lane >> 4, r15 = lane & 15;
    const bf16* Abase = A + ((size_t)(b * 512 + ct * 64)) * 512;
    const bf16* Bbase = B + ((size_t)(pt * 128)) * 512;
    const int sr = t >> 2, sc = (t & 3) * 8;
    f32x4 acc[8] = {};
    for (int k0 = 0; k0 < 512; k0 += 32) {
        GLL16(Abase + (size_t)sr * 512 + k0 + sc, As + t * 8);
        GLL16(Bbase + (size_t)sr * 512 + k0 + sc, Bs + t * 8);
        GLL16(Bbase + (size_t)(sr + 64) * 512 + k0 + sc, Bs + (t + 256) * 8);
        __syncthreads();
        bf16x8 af = *(const bf16x8*)(As + (w * 16 + r15) * 32 + quad * 8);
#pragma unroll
        for (int j = 0; j < 8; ++j) {
            bf16x8 bfr = *(const bf16x8*)(Bs + (j * 16 + r15) * 32 + quad * 8);
            acc[j] = __builtin_amdgcn_mfma_f32_16x16x32_bf16(af, bfr, acc[j], 0, 0, 0);
        }
        __syncthreads();
    }
    float lam = lamp[0];
    size_t rowbase = (size_t)(b * 512 + ct * 64 + w * 16 + quad * 4);
#pragma unroll
    for (int j = 0; j < 8; ++j)
#pragma unroll
        for (int ii = 0; ii < 4; ++ii) {
            size_t idx = (rowbase + ii) * 1024 + pt * 128 + j * 16 + r15;
            out[idx] = fq[idx] + lam * acc[j][ii];
        }
}

// K6: fused logits + softmax. One block per row z (32 blocks).
// z<16: alpha row -> out; z>=16: beta row -> ws.
__global__ void k_logsoft(const float* __restrict__ tbp, const float* __restrict__ r,
                          const float* __restrict__ wsq, const float* __restrict__ wsk,
                          const float* __restrict__ fsm32, float* __restrict__ alpha_out,
                          float* __restrict__ beta) {
    __shared__ float coef[512];
    __shared__ float red[4];
    int z = blockIdx.x;
    int t = threadIdx.x;
    int w = t >> 6, lane = t & 63;
    // build 512-entry coefficient vector
    if (z < 16) {
#pragma unroll
        for (int j = 0; j < 2; ++j) {
            int d = t + 256 * j;
            coef[d] = tbp[z * 512 + d] + tbp[(16 + z) * 512 + d];
        }
    } else {
        int b = z - 16;
#pragma unroll
        for (int j = 0; j < 2; ++j) {
            int c = t + 256 * j;
            coef[c] = r[b * 512 + c] * wsq[c] * wsk[c] * (1.f / 256.f);
        }
    }
    __syncthreads();
    float v[4] = {0.f, 0.f, 0.f, 0.f};
    for (int d = 0; d < 512; ++d) {
        float cv = coef[d];
        const float* row = fsm32 + (size_t)d * 1024 + t;
#pragma unroll
        for (int j = 0; j < 4; ++j) v[j] = fmaf(cv, row[256 * j], v[j]);
    }
    float mx = fmaxf(fmaxf(v[0], v[1]), fmaxf(v[2], v[3]));
    float wm = wave_reduce_max(mx);
    if (lane == 0) red[w] = wm;
    __syncthreads();
    mx = fmaxf(fmaxf(red[0], red[1]), fmaxf(red[2], red[3]));
    float s = 0.f;
#pragma unroll
    for (int j = 0; j < 4; ++j) {
        v[j] = __expf(v[j] - mx);
        s += v[j];
    }
    __syncthreads();
    float ws_ = wave_reduce_sum(s);
    if (lane == 0) red[w] = ws_;
    __syncthreads();
    s = red[0] + red[1] + red[2] + red[3];
    float inv = 1.f / s;
    if (z < 16) {
#pragma unroll
        for (int j = 0; j < 4; ++j) alpha_out[(size_t)z * 1024 + t + 256 * j] = v[j] * inv;
    } else {
#pragma unroll
        for (int j = 0; j < 4; ++j) beta[(size_t)(z - 16) * 1024 + t + 256 * j] = v[j] * inv;
    }
}

// K7: beta_mean broadcast
__global__ void k_betamean(const float* __restrict__ beta, float* __restrict__ out) {
    int q = blockIdx.x * 256 + threadIdx.x;
    float s = 0.f;
#pragma unroll
    for (int b = 0; b < 16; ++b) s += beta[b * 1024 + q];
    float val = s * (1.f / 16.f);
#pragma unroll
    for (int si = 0; si < 16; ++si) out[(size_t)si * 1024 + q] = val;
}

extern "C" void kernel_launch(void* const* d_in, const int* in_sizes, int n_in,
                              void* d_out, int out_size, void* d_ws, size_t ws_size,
                              hipStream_t stream) {
    const float* f_q = (const float*)d_in[0];
    const float* f_s = (const float*)d_in[1];
    const float* w_cca_q = (const float*)d_in[2];
    const float* w_cca_k = (const float*)d_in[3];
    const float* w_cca_v = (const float*)d_in[4];
    const float* w_sca_q = (const float*)d_in[5];
    const float* w_sca_k = (const float*)d_in[6];
    const float* lamp = (const float*)d_in[7];

    char* ws = (char*)d_ws;
    float* fsm32 = (float*)(ws + 0);             //  2 MB   [512,1024]
    bf16* fsm16 = (bf16*)(ws + 2097152);         //  1 MB
    bf16* fsmT = (bf16*)(ws + 3145728);          //  1 MB   [1024,512]
    float* G = (float*)(ws + 4194304);           // 16 MB   [16,512,512]
    bf16* Acw = (bf16*)(ws + 20971520);          //  8 MB   [16,512,512]
    float* rm = (float*)(ws + 29360128);         //  2 KB
    float* u = (float*)(ws + 29362176);          //  2 KB
    float* r = (float*)(ws + 29364224);          // 32 KB   [16,512]
    float* tbp = (float*)(ws + 29396992);        // 64 KB   [32,512]
    float* beta = (float*)(ws + 29462528);       // 64 KB

    float* out_fq = (float*)d_out;
    float* out_alpha = out_fq + 8388608;
    float* out_bmean = out_fq + 8404992;

    k_prep<<<dim3(32, 16), 256, 0, stream>>>(f_s, fsm32, fsm16, fsmT);
    k_u<<<512, 256, 0, stream>>>(fsm32, w_sca_q, w_sca_k, u, rm);
    k_gemm1<<<dim3(4, 8, 16), 256, 0, stream>>>(f_q, fsm16, G);
    k_softmax_ac<<<2048, 256, 0, stream>>>(G, w_cca_q, w_cca_k, w_cca_v, rm, Acw, r);
    k_t<<<dim3(2, 16, 2), 256, 0, stream>>>(Acw, u, tbp);
    k_gemm2<<<dim3(8, 8, 16), 256, 0, stream>>>(Acw, fsmT, f_q, lamp, out_fq);
    k_logsoft<<<32, 256, 0, stream>>>(tbp, r, w_sca_q, w_sca_k, fsm32, out_alpha, beta);
    k_betamean<<<4, 256, 0, stream>>>(beta, out_bmean);
}